// Round 1
// baseline (810.704 us; speedup 1.0000x reference)
//
#include <hip/hip_runtime.h>
#include <math.h>

#define DIM 2048
#define NH 16
#define HD 128
#define NB 32
#define BS 16
#define BPS 64
#define KC 32

// ---------------- RMSNorm: one block per batch row ----------------
__global__ __launch_bounds__(256)
void rms_kernel(const float* __restrict__ in, const float* __restrict__ w,
                float* __restrict__ out)
{
    const int b = blockIdx.x;
    const int tid = threadIdx.x;
    const float* row = in + (size_t)b * DIM;
    const float4 a0 = *(const float4*)(row + tid * 8);
    const float4 a1 = *(const float4*)(row + tid * 8 + 4);
    float ss = a0.x*a0.x + a0.y*a0.y + a0.z*a0.z + a0.w*a0.w
             + a1.x*a1.x + a1.y*a1.y + a1.z*a1.z + a1.w*a1.w;
    ss += __shfl_xor(ss, 1);  ss += __shfl_xor(ss, 2);  ss += __shfl_xor(ss, 4);
    ss += __shfl_xor(ss, 8);  ss += __shfl_xor(ss, 16); ss += __shfl_xor(ss, 32);
    __shared__ float red[4];
    if ((tid & 63) == 0) red[tid >> 6] = ss;
    __syncthreads();
    const float mean = (red[0] + red[1] + red[2] + red[3]) * (1.0f / (float)DIM);
    const float r = rsqrtf(mean + 1e-5f);
    const float4 w0 = *(const float4*)(w + tid * 8);
    const float4 w1 = *(const float4*)(w + tid * 8 + 4);
    float4 o0, o1;
    o0.x = a0.x * r * w0.x; o0.y = a0.y * r * w0.y; o0.z = a0.z * r * w0.z; o0.w = a0.w * r * w0.w;
    o1.x = a1.x * r * w1.x; o1.y = a1.y * r * w1.y; o1.z = a1.z * r * w1.z; o1.w = a1.w * r * w1.w;
    *(float4*)(out + (size_t)b * DIM + tid * 8)     = o0;
    *(float4*)(out + (size_t)b * DIM + tid * 8 + 4) = o1;
}

// ---------------- split-K skinny GEMM: C[m][b] partial = sum_k W[m][k] * act[b][k]
// grid: (M/128, KS). Block: 256 thr, 128 rows x 32 batches, K-chunk KC=32.
// W tile staged K-major (padded 132) -> contiguous b128 compute reads.
__global__ __launch_bounds__(256)
void gemm_splitk(const float* __restrict__ W0, const float* __restrict__ W1,
                 const float* __restrict__ W2, int rows_per_w,
                 const float* __restrict__ act, int K, int Kblk,
                 float* __restrict__ partial, int M)
{
    __shared__ float Wt[KC][132];
    __shared__ float ht[KC][36];
    const int tid = threadIdx.x;
    const int m0 = blockIdx.x * 128;
    const int wi = m0 / rows_per_w;
    const float* __restrict__ W = (wi == 0) ? W0 : ((wi == 1) ? W1 : W2);
    const int row0 = m0 - wi * rows_per_w;
    const int k0b = blockIdx.y * Kblk;
    const int tr = tid & 31;          // row group (4 rows)
    const int tb = tid >> 5;          // batch group (4 batches)
    const int sr = tid >> 3;          // staging: row / batch index 0..31
    const int skq = (tid & 7) * 4;    // staging: k offset 0,4,...,28

    float acc[4][4];
    #pragma unroll
    for (int i = 0; i < 4; i++) { acc[i][0]=0.f; acc[i][1]=0.f; acc[i][2]=0.f; acc[i][3]=0.f; }

    for (int k0 = k0b; k0 < k0b + Kblk; k0 += KC) {
        // stage W chunk: rows sr, sr+32, sr+64, sr+96 ; k quad skq (coalesced 128B/row)
        #pragma unroll
        for (int j = 0; j < 4; j++) {
            const int r = sr + j * 32;
            const float4 w4 = *(const float4*)(W + (size_t)(row0 + r) * K + k0 + skq);
            Wt[skq + 0][r] = w4.x; Wt[skq + 1][r] = w4.y;
            Wt[skq + 2][r] = w4.z; Wt[skq + 3][r] = w4.w;
        }
        // stage act chunk: batch sr, k quad skq
        {
            const float4 h4 = *(const float4*)(act + (size_t)sr * K + k0 + skq);
            ht[skq + 0][sr] = h4.x; ht[skq + 1][sr] = h4.y;
            ht[skq + 2][sr] = h4.z; ht[skq + 3][sr] = h4.w;
        }
        __syncthreads();
        #pragma unroll
        for (int k = 0; k < KC; k++) {
            const float4 w4 = *(const float4*)&Wt[k][tr * 4];
            const float4 h4 = *(const float4*)&ht[k][tb * 4];
            acc[0][0] += w4.x*h4.x; acc[0][1] += w4.x*h4.y; acc[0][2] += w4.x*h4.z; acc[0][3] += w4.x*h4.w;
            acc[1][0] += w4.y*h4.x; acc[1][1] += w4.y*h4.y; acc[1][2] += w4.y*h4.z; acc[1][3] += w4.y*h4.w;
            acc[2][0] += w4.z*h4.x; acc[2][1] += w4.z*h4.y; acc[2][2] += w4.z*h4.z; acc[2][3] += w4.z*h4.w;
            acc[3][0] += w4.w*h4.x; acc[3][1] += w4.w*h4.y; acc[3][2] += w4.w*h4.z; acc[3][3] += w4.w*h4.w;
        }
        __syncthreads();
    }
    #pragma unroll
    for (int i = 0; i < 4; i++) {
        const float4 o = make_float4(acc[i][0], acc[i][1], acc[i][2], acc[i][3]);
        *(float4*)(partial + ((size_t)blockIdx.y * M + m0 + tr * 4 + i) * 32 + tb * 4) = o;
    }
}

// ---------------- reduce kernels ----------------
__global__ __launch_bounds__(256)
void reduce_qkv(const float* __restrict__ partial, float* __restrict__ q,
                float* __restrict__ kn, float* __restrict__ vn)
{
    const int e = blockIdx.x * 256 + threadIdx.x;   // over 6144*32
    const int m = e >> 5, b = e & 31;
    float s = 0.f;
    #pragma unroll
    for (int ks = 0; ks < 16; ks++) s += partial[((size_t)ks * 6144 + m) * 32 + b];
    if (m < 2048)      q [(size_t)b * DIM + m]        = s;
    else if (m < 4096) kn[(size_t)b * DIM + (m-2048)] = s;
    else               vn[(size_t)b * DIM + (m-4096)] = s;
}

__global__ __launch_bounds__(256)
void reduce_add(const float* __restrict__ partial, int KS, int M,
                const float* __restrict__ resid, float* __restrict__ out)
{
    const int e = blockIdx.x * 256 + threadIdx.x;   // over M*32
    const int m = e >> 5, b = e & 31;
    float s = 0.f;
    for (int ks = 0; ks < KS; ks++) s += partial[((size_t)ks * M + m) * 32 + b];
    out[(size_t)b * M + m] = s + resid[(size_t)b * M + m];
}

__global__ __launch_bounds__(256)
void reduce_m13(const float* __restrict__ partial, float* __restrict__ a)
{
    const int e = blockIdx.x * 256 + threadIdx.x;   // over 8192*32
    const int j = e >> 5, b = e & 31;
    float g = 0.f, u = 0.f;
    #pragma unroll
    for (int ks = 0; ks < 4; ks++) {
        g += partial[((size_t)ks * 16384 + j) * 32 + b];
        u += partial[((size_t)ks * 16384 + 8192 + j) * 32 + b];
    }
    const float sg = g / (1.0f + __expf(-g));   // silu
    a[(size_t)b * 8192 + j] = sg * u;
}

// ---------------- paged attention: one block per (batch, head) ----------------
__global__ __launch_bounds__(256)
void attn_kernel(const float* __restrict__ q, const float* __restrict__ kn,
                 const float* __restrict__ vn, const float* __restrict__ key_heap,
                 const float* __restrict__ val_heap, const int* __restrict__ block_table,
                 const int* __restrict__ context_lens, float* __restrict__ attn_out)
{
    const int b  = blockIdx.x >> 4;
    const int hd = blockIdx.x & 15;
    const int tid  = threadIdx.x;
    const int wave = tid >> 6;
    const int lane = tid & 63;
    const int ps = lane >> 5;      // position sub (0/1)
    const int dl = lane & 31;      // dim lane: 4 floats each
    const int ctxv = context_lens[b];

    __shared__ int   bt[BPS];
    __shared__ float sc[1024];
    __shared__ float red[8];
    __shared__ float wb[4][HD];

    if (tid < BPS) bt[tid] = block_table[b * BPS + tid];
    const float4 q4 = *(const float4*)(q + (size_t)b * DIM + hd * HD + dl * 4);
    __syncthreads();

    // --- QK^T ---
    for (int s0 = wave * 2 + ps; s0 < ctxv; s0 += 8) {
        const float* kp = (s0 == ctxv - 1)
            ? (kn + (size_t)b * DIM + hd * HD)
            : (key_heap + ((size_t)(bt[s0 >> 4] * BS + (s0 & 15)) * NH + hd) * HD);
        const float4 k4 = *(const float4*)(kp + dl * 4);
        float d = q4.x*k4.x + q4.y*k4.y + q4.z*k4.z + q4.w*k4.w;
        d += __shfl_xor(d, 1); d += __shfl_xor(d, 2); d += __shfl_xor(d, 4);
        d += __shfl_xor(d, 8); d += __shfl_xor(d, 16);
        if (dl == 0) sc[s0] = d;
    }
    __syncthreads();

    // --- softmax ---
    float lm = -INFINITY;
    for (int i = tid; i < ctxv; i += 256) lm = fmaxf(lm, sc[i]);
    lm = fmaxf(lm, __shfl_xor(lm, 1));  lm = fmaxf(lm, __shfl_xor(lm, 2));
    lm = fmaxf(lm, __shfl_xor(lm, 4));  lm = fmaxf(lm, __shfl_xor(lm, 8));
    lm = fmaxf(lm, __shfl_xor(lm, 16)); lm = fmaxf(lm, __shfl_xor(lm, 32));
    if ((tid & 63) == 0) red[tid >> 6] = lm;
    __syncthreads();
    const float Mx = fmaxf(fmaxf(red[0], red[1]), fmaxf(red[2], red[3]));
    const float scale = 0.08838834764831845f;   // 1/sqrt(128)
    float lsum = 0.f;
    for (int i = tid; i < ctxv; i += 256) {
        const float p = __expf((sc[i] - Mx) * scale);
        sc[i] = p; lsum += p;
    }
    lsum += __shfl_xor(lsum, 1);  lsum += __shfl_xor(lsum, 2);  lsum += __shfl_xor(lsum, 4);
    lsum += __shfl_xor(lsum, 8);  lsum += __shfl_xor(lsum, 16); lsum += __shfl_xor(lsum, 32);
    if ((tid & 63) == 0) red[4 + (tid >> 6)] = lsum;
    __syncthreads();
    const float inv = 1.0f / (red[4] + red[5] + red[6] + red[7]);

    // --- PV ---
    float4 acc = make_float4(0.f, 0.f, 0.f, 0.f);
    for (int s0 = wave * 2 + ps; s0 < ctxv; s0 += 8) {
        const float* vp = (s0 == ctxv - 1)
            ? (vn + (size_t)b * DIM + hd * HD)
            : (val_heap + ((size_t)(bt[s0 >> 4] * BS + (s0 & 15)) * NH + hd) * HD);
        const float4 v4 = *(const float4*)(vp + dl * 4);
        const float p = sc[s0];
        acc.x += p * v4.x; acc.y += p * v4.y; acc.z += p * v4.z; acc.w += p * v4.w;
    }
    acc.x += __shfl_xor(acc.x, 32); acc.y += __shfl_xor(acc.y, 32);
    acc.z += __shfl_xor(acc.z, 32); acc.w += __shfl_xor(acc.w, 32);
    if (lane < 32) *(float4*)&wb[wave][dl * 4] = acc;
    __syncthreads();
    if (tid < HD) {
        const float o = (wb[0][tid] + wb[1][tid] + wb[2][tid] + wb[3][tid]) * inv;
        attn_out[(size_t)b * DIM + hd * HD + tid] = o;
    }
}

// ---------------- launch ----------------
extern "C" void kernel_launch(void* const* d_in, const int* in_sizes, int n_in,
                              void* d_out, int out_size, void* d_ws, size_t ws_size,
                              hipStream_t stream)
{
    const float* x        = (const float*)d_in[0];
    const float* key_heap = (const float*)d_in[1];
    const float* val_heap = (const float*)d_in[2];
    const float* wq = (const float*)d_in[3];
    const float* wk = (const float*)d_in[4];
    const float* wv = (const float*)d_in[5];
    const float* wo = (const float*)d_in[6];
    const float* w1 = (const float*)d_in[7];
    const float* w2 = (const float*)d_in[8];
    const float* w3 = (const float*)d_in[9];
    const float* n1w = (const float*)d_in[10];
    const float* n2w = (const float*)d_in[11];
    const int* btab = (const int*)d_in[12];
    const int* ctx  = (const int*)d_in[14];
    float* out = (float*)d_out;

    float* ws = (float*)d_ws;          // needs ~15.5 MB of fp32 scratch
    float* h1   = ws;                  // [32][2048]
    float* qb   = ws + 65536;          // [32][2048]
    float* kn   = ws + 131072;         // [32][2048]
    float* vn   = ws + 196608;         // [32][2048]
    float* attn = ws + 262144;         // [32][2048]
    float* x2   = ws + 327680;         // [32][2048]
    float* h2   = ws + 393216;         // [32][2048]
    float* ab   = ws + 458752;         // [32][8192]
    float* pt   = ws + 720896;         // partials, max 16*6144*32 floats

    // x -> h1
    rms_kernel<<<32, 256, 0, stream>>>(x, n1w, h1);
    // QKV: M=6144 (wq|wk|wv), K=2048, KS=16
    gemm_splitk<<<dim3(48, 16), 256, 0, stream>>>(wq, wk, wv, 2048, h1, 2048, 128, pt, 6144);
    reduce_qkv<<<768, 256, 0, stream>>>(pt, qb, kn, vn);
    // paged attention
    attn_kernel<<<512, 256, 0, stream>>>(qb, kn, vn, key_heap, val_heap, btab, ctx, attn);
    // O-proj: M=2048, K=2048, KS=32 ; +x residual
    gemm_splitk<<<dim3(16, 32), 256, 0, stream>>>(wo, wo, wo, 2048, attn, 2048, 64, pt, 2048);
    reduce_add<<<256, 256, 0, stream>>>(pt, 32, 2048, x, x2);
    // x2 -> h2
    rms_kernel<<<32, 256, 0, stream>>>(x2, n2w, h2);
    // MLP w1|w3: M=16384, K=2048, KS=4 ; silu(g)*u
    gemm_splitk<<<dim3(128, 4), 256, 0, stream>>>(w1, w3, w3, 8192, h2, 2048, 512, pt, 16384);
    reduce_m13<<<1024, 256, 0, stream>>>(pt, ab);
    // MLP w2: M=2048, K=8192, KS=32 ; +x2 residual
    gemm_splitk<<<dim3(16, 32), 256, 0, stream>>>(w2, w2, w2, 2048, ab, 8192, 256, pt, 2048);
    reduce_add<<<256, 256, 0, stream>>>(pt, 32, 2048, x2, out);
}

// Round 6
// 722.445 us; speedup vs baseline: 1.1222x; 1.1222x over previous
//
#include <hip/hip_runtime.h>
#include <math.h>

#define DIM 2048
#define NH 16
#define HD 128
#define BS 16
#define BPS 64
#define KC 32
#define CS 128          // attention context chunk per split block
#define NSPLIT 8        // 1024 / 128

// ---------------- RMSNorm: one block per batch row ----------------
__global__ __launch_bounds__(256)
void rms_kernel(const float* __restrict__ in, const float* __restrict__ w,
                float* __restrict__ out)
{
    const int b = blockIdx.x;
    const int tid = threadIdx.x;
    const float* row = in + (size_t)b * DIM;
    const float4 a0 = *(const float4*)(row + tid * 8);
    const float4 a1 = *(const float4*)(row + tid * 8 + 4);
    float ss = a0.x*a0.x + a0.y*a0.y + a0.z*a0.z + a0.w*a0.w
             + a1.x*a1.x + a1.y*a1.y + a1.z*a1.z + a1.w*a1.w;
    ss += __shfl_xor(ss, 1);  ss += __shfl_xor(ss, 2);  ss += __shfl_xor(ss, 4);
    ss += __shfl_xor(ss, 8);  ss += __shfl_xor(ss, 16); ss += __shfl_xor(ss, 32);
    __shared__ float red[4];
    if ((tid & 63) == 0) red[tid >> 6] = ss;
    __syncthreads();
    const float mean = (red[0] + red[1] + red[2] + red[3]) * (1.0f / (float)DIM);
    const float r = rsqrtf(mean + 1e-5f);
    const float4 w0 = *(const float4*)(w + tid * 8);
    const float4 w1 = *(const float4*)(w + tid * 8 + 4);
    float4 o0, o1;
    o0.x = a0.x * r * w0.x; o0.y = a0.y * r * w0.y; o0.z = a0.z * r * w0.z; o0.w = a0.w * r * w0.w;
    o1.x = a1.x * r * w1.x; o1.y = a1.y * r * w1.y; o1.z = a1.z * r * w1.z; o1.w = a1.w * r * w1.w;
    *(float4*)(out + (size_t)b * DIM + tid * 8)     = o0;
    *(float4*)(out + (size_t)b * DIM + tid * 8 + 4) = o1;
}

// ---------------- split-K skinny GEMM ----------------
// C[m][b] partial = sum_k W[m][k] * act[b][k]
// grid: (M/128, KS). 256 thr: 128 rows x 32 batches, thread tile 2 rows x 8 batches.
// Register double-buffer: prefetch next K-chunk during compute.
__global__ __launch_bounds__(256)
void gemm_splitk(const float* __restrict__ W0, const float* __restrict__ W1,
                 const float* __restrict__ W2, int rows_per_w,
                 const float* __restrict__ act, int K, int Kblk,
                 float* __restrict__ partial, int M)
{
    __shared__ float Wt[KC][130];   // K-major, pad 130 (even) -> conflict-free b64 reads
    __shared__ float ht[KC][36];
    const int tid = threadIdx.x;
    const int m0 = blockIdx.x * 128;
    const int wi = m0 / rows_per_w;
    const float* __restrict__ W = (wi == 0) ? W0 : ((wi == 1) ? W1 : W2);
    const int row0 = m0 - wi * rows_per_w;
    const int k0b = blockIdx.y * Kblk;
    const int tr2 = tid & 63;         // 2 rows each: r = tr2*2
    const int tbg = tid >> 6;         // batch group of 8: b0 = tbg*8
    const int sr  = tid >> 3;         // staging row/batch 0..31
    const int skq = (tid & 7) * 4;    // staging k quad

    const int nchunk = Kblk / KC;
    float4 wreg[4];
    float4 hreg;
    int k0 = k0b;
    #pragma unroll
    for (int j = 0; j < 4; j++)
        wreg[j] = *(const float4*)(W + (size_t)(row0 + sr + j * 32) * K + k0 + skq);
    hreg = *(const float4*)(act + (size_t)sr * K + k0 + skq);

    float acc[2][8];
    #pragma unroll
    for (int i = 0; i < 2; i++)
        #pragma unroll
        for (int j = 0; j < 8; j++) acc[i][j] = 0.f;

    for (int c = 0; c < nchunk; c++) {
        // drain staged regs to LDS
        #pragma unroll
        for (int j = 0; j < 4; j++) {
            const int r = sr + j * 32;
            Wt[skq + 0][r] = wreg[j].x; Wt[skq + 1][r] = wreg[j].y;
            Wt[skq + 2][r] = wreg[j].z; Wt[skq + 3][r] = wreg[j].w;
        }
        ht[skq + 0][sr] = hreg.x; ht[skq + 1][sr] = hreg.y;
        ht[skq + 2][sr] = hreg.z; ht[skq + 3][sr] = hreg.w;
        __syncthreads();
        // prefetch next chunk (latency hides under compute below)
        if (c + 1 < nchunk) {
            const int k1 = k0 + KC;
            #pragma unroll
            for (int j = 0; j < 4; j++)
                wreg[j] = *(const float4*)(W + (size_t)(row0 + sr + j * 32) * K + k1 + skq);
            hreg = *(const float4*)(act + (size_t)sr * K + k1 + skq);
        }
        #pragma unroll
        for (int k = 0; k < KC; k++) {
            const float2 w2v = *(const float2*)&Wt[k][tr2 * 2];
            const float4 h0  = *(const float4*)&ht[k][tbg * 8];
            const float4 h1  = *(const float4*)&ht[k][tbg * 8 + 4];
            acc[0][0] += w2v.x*h0.x; acc[0][1] += w2v.x*h0.y; acc[0][2] += w2v.x*h0.z; acc[0][3] += w2v.x*h0.w;
            acc[0][4] += w2v.x*h1.x; acc[0][5] += w2v.x*h1.y; acc[0][6] += w2v.x*h1.z; acc[0][7] += w2v.x*h1.w;
            acc[1][0] += w2v.y*h0.x; acc[1][1] += w2v.y*h0.y; acc[1][2] += w2v.y*h0.z; acc[1][3] += w2v.y*h0.w;
            acc[1][4] += w2v.y*h1.x; acc[1][5] += w2v.y*h1.y; acc[1][6] += w2v.y*h1.z; acc[1][7] += w2v.y*h1.w;
        }
        __syncthreads();
        k0 += KC;
    }
    #pragma unroll
    for (int i = 0; i < 2; i++) {
        float* p = partial + ((size_t)blockIdx.y * M + m0 + tr2 * 2 + i) * 32 + tbg * 8;
        *(float4*)p       = make_float4(acc[i][0], acc[i][1], acc[i][2], acc[i][3]);
        *(float4*)(p + 4) = make_float4(acc[i][4], acc[i][5], acc[i][6], acc[i][7]);
    }
}

// ---------------- reduce kernels ----------------
__global__ __launch_bounds__(256)
void reduce_qkv(const float* __restrict__ partial, float* __restrict__ q,
                float* __restrict__ kn, float* __restrict__ vn)
{
    const int e = blockIdx.x * 256 + threadIdx.x;   // over 6144*32
    const int m = e >> 5, b = e & 31;
    float s = 0.f;
    #pragma unroll
    for (int ks = 0; ks < 16; ks++) s += partial[((size_t)ks * 6144 + m) * 32 + b];
    if (m < 2048)      q [(size_t)b * DIM + m]        = s;
    else if (m < 4096) kn[(size_t)b * DIM + (m-2048)] = s;
    else               vn[(size_t)b * DIM + (m-4096)] = s;
}

__global__ __launch_bounds__(256)
void reduce_add(const float* __restrict__ partial, int KS, int M,
                const float* __restrict__ resid, float* __restrict__ out)
{
    const int e = blockIdx.x * 256 + threadIdx.x;   // over M*32
    const int m = e >> 5, b = e & 31;
    float s = 0.f;
    for (int ks = 0; ks < KS; ks++) s += partial[((size_t)ks * M + m) * 32 + b];
    out[(size_t)b * M + m] = s + resid[(size_t)b * M + m];
}

__global__ __launch_bounds__(256)
void reduce_m13(const float* __restrict__ partial, float* __restrict__ a)
{
    const int e = blockIdx.x * 256 + threadIdx.x;   // over 8192*32
    const int j = e >> 5, b = e & 31;
    float g = 0.f, u = 0.f;
    #pragma unroll
    for (int ks = 0; ks < 4; ks++) {
        g += partial[((size_t)ks * 16384 + j) * 32 + b];
        u += partial[((size_t)ks * 16384 + 8192 + j) * 32 + b];
    }
    const float sg = g / (1.0f + __expf(-g));   // silu
    a[(size_t)b * 8192 + j] = sg * u;
}

// ---------------- flash-decoding paged attention ----------------
// grid: 32*16*8 = 4096 blocks; block handles one 128-position chunk of one (b,head).
// Writes unnormalized partial O[128] + (raw max m, local expsum l).
__global__ __launch_bounds__(256)
void attn_split(const float* __restrict__ q, const float* __restrict__ kn,
                const float* __restrict__ vn, const float* __restrict__ key_heap,
                const float* __restrict__ val_heap, const int* __restrict__ block_table,
                const int* __restrict__ context_lens,
                float* __restrict__ pao, float* __restrict__ pml)
{
    const int split = blockIdx.x & 7;
    const int hd    = (blockIdx.x >> 3) & 15;
    const int b     = blockIdx.x >> 7;
    const int ctxv  = context_lens[b];
    const int s_begin = split * CS;
    if (s_begin >= ctxv) return;
    const int cnt = min(CS, ctxv - s_begin);

    const int tid  = threadIdx.x;
    const int wave = tid >> 6;
    const int lane = tid & 63;
    const int ps = lane >> 5;      // position sub (0/1)
    const int dl = lane & 31;      // dim lane: 4 floats each

    __shared__ int   bt8[8];
    __shared__ float sc[CS];
    __shared__ float red[8];
    __shared__ float wb[4][HD];

    if (tid < 8) bt8[tid] = block_table[b * BPS + (s_begin >> 4) + tid];
    const float4 q4 = *(const float4*)(q + (size_t)b * DIM + hd * HD + dl * 4);
    __syncthreads();

    // --- QK^T over this chunk ---
    for (int i = wave * 2 + ps; i < cnt; i += 8) {
        const int s = s_begin + i;
        const float* kp = (s == ctxv - 1)
            ? (kn + (size_t)b * DIM + hd * HD)
            : (key_heap + ((size_t)(bt8[i >> 4] * BS + (s & 15)) * NH + hd) * HD);
        const float4 k4 = *(const float4*)(kp + dl * 4);
        float d = q4.x*k4.x + q4.y*k4.y + q4.z*k4.z + q4.w*k4.w;
        d += __shfl_xor(d, 1); d += __shfl_xor(d, 2); d += __shfl_xor(d, 4);
        d += __shfl_xor(d, 8); d += __shfl_xor(d, 16);
        if (dl == 0) sc[i] = d;
    }
    __syncthreads();

    // --- local softmax (unnormalized) ---
    float lm = (tid < cnt) ? sc[tid] : -INFINITY;
    lm = fmaxf(lm, __shfl_xor(lm, 1));  lm = fmaxf(lm, __shfl_xor(lm, 2));
    lm = fmaxf(lm, __shfl_xor(lm, 4));  lm = fmaxf(lm, __shfl_xor(lm, 8));
    lm = fmaxf(lm, __shfl_xor(lm, 16)); lm = fmaxf(lm, __shfl_xor(lm, 32));
    if ((tid & 63) == 0) red[tid >> 6] = lm;
    __syncthreads();
    const float Mx = fmaxf(fmaxf(red[0], red[1]), fmaxf(red[2], red[3]));
    const float scale = 0.08838834764831845f;   // 1/sqrt(128)
    float lsum = 0.f;
    if (tid < cnt) {
        const float p = __expf((sc[tid] - Mx) * scale);
        sc[tid] = p; lsum = p;
    }
    lsum += __shfl_xor(lsum, 1);  lsum += __shfl_xor(lsum, 2);  lsum += __shfl_xor(lsum, 4);
    lsum += __shfl_xor(lsum, 8);  lsum += __shfl_xor(lsum, 16); lsum += __shfl_xor(lsum, 32);
    if ((tid & 63) == 0) red[4 + (tid >> 6)] = lsum;
    __syncthreads();

    // --- partial PV (unnormalized) ---
    float4 acc = make_float4(0.f, 0.f, 0.f, 0.f);
    for (int i = wave * 2 + ps; i < cnt; i += 8) {
        const int s = s_begin + i;
        const float* vp = (s == ctxv - 1)
            ? (vn + (size_t)b * DIM + hd * HD)
            : (val_heap + ((size_t)(bt8[i >> 4] * BS + (s & 15)) * NH + hd) * HD);
        const float4 v4 = *(const float4*)(vp + dl * 4);
        const float p = sc[i];
        acc.x += p * v4.x; acc.y += p * v4.y; acc.z += p * v4.z; acc.w += p * v4.w;
    }
    acc.x += __shfl_xor(acc.x, 32); acc.y += __shfl_xor(acc.y, 32);
    acc.z += __shfl_xor(acc.z, 32); acc.w += __shfl_xor(acc.w, 32);
    if (lane < 32) *(float4*)&wb[wave][dl * 4] = acc;
    __syncthreads();
    if (tid < HD) {
        pao[(size_t)blockIdx.x * HD + tid] = wb[0][tid] + wb[1][tid] + wb[2][tid] + wb[3][tid];
    }
    if (tid == 0) {
        pml[(size_t)blockIdx.x * 2]     = Mx;
        pml[(size_t)blockIdx.x * 2 + 1] = red[4] + red[5] + red[6] + red[7];
    }
}

// combine splits: grid 512 (b*16+h), 128 threads (one per d)
__global__ __launch_bounds__(128)
void attn_reduce(const float* __restrict__ pao, const float* __restrict__ pml,
                 const int* __restrict__ context_lens, float* __restrict__ attn_out)
{
    const int bh = blockIdx.x;
    const int b  = bh >> 4;
    const int d  = threadIdx.x;
    const int ns = (context_lens[b] + CS - 1) >> 7;
    const float scale = 0.08838834764831845f;
    float M = -INFINITY;
    float ml[NSPLIT], ll[NSPLIT];
    for (int s = 0; s < ns; s++) {
        ml[s] = pml[((size_t)bh * NSPLIT + s) * 2];
        ll[s] = pml[((size_t)bh * NSPLIT + s) * 2 + 1];
        M = fmaxf(M, ml[s]);
    }
    float L = 0.f, o = 0.f;
    for (int s = 0; s < ns; s++) {
        const float f = __expf((ml[s] - M) * scale);
        L += ll[s] * f;
        o += pao[((size_t)bh * NSPLIT + s) * HD + d] * f;
    }
    attn_out[(size_t)bh * HD + d] = o / L;
}

// ---------------- launch ----------------
extern "C" void kernel_launch(void* const* d_in, const int* in_sizes, int n_in,
                              void* d_out, int out_size, void* d_ws, size_t ws_size,
                              hipStream_t stream)
{
    const float* x        = (const float*)d_in[0];
    const float* key_heap = (const float*)d_in[1];
    const float* val_heap = (const float*)d_in[2];
    const float* wq = (const float*)d_in[3];
    const float* wk = (const float*)d_in[4];
    const float* wv = (const float*)d_in[5];
    const float* wo = (const float*)d_in[6];
    const float* w1 = (const float*)d_in[7];
    const float* w2 = (const float*)d_in[8];
    const float* w3 = (const float*)d_in[9];
    const float* n1w = (const float*)d_in[10];
    const float* n2w = (const float*)d_in[11];
    const int* btab = (const int*)d_in[12];
    const int* ctx  = (const int*)d_in[14];
    float* out = (float*)d_out;

    float* ws = (float*)d_ws;          // ~15.5 MB fp32 scratch (same as round 1)
    float* h1   = ws;                  // [32][2048]
    float* qb   = ws + 65536;
    float* kn   = ws + 131072;
    float* vn   = ws + 196608;
    float* attn = ws + 262144;
    float* x2   = ws + 327680;
    float* h2   = ws + 393216;
    float* ab   = ws + 458752;         // [32][8192]
    float* pt   = ws + 720896;         // GEMM partials (max 16*6144*32 floats)
    // attention partials overlay pt (QKV partials are dead once reduce_qkv ran;
    // pt is rewritten only by the O-proj GEMM, after attn_reduce consumed these)
    float* pao  = ws + 720896;         // [4096][128]
    float* pml  = ws + 720896 + 524288; // [4096][2]

    rms_kernel<<<32, 256, 0, stream>>>(x, n1w, h1);
    // QKV: M=6144, K=2048, KS=16 (Kblk=128, 4 chunks)
    gemm_splitk<<<dim3(48, 16), 256, 0, stream>>>(wq, wk, wv, 2048, h1, 2048, 128, pt, 6144);
    reduce_qkv<<<768, 256, 0, stream>>>(pt, qb, kn, vn);
    // flash-decoding paged attention
    attn_split<<<4096, 256, 0, stream>>>(qb, kn, vn, key_heap, val_heap, btab, ctx, pao, pml);
    attn_reduce<<<512, 128, 0, stream>>>(pao, pml, ctx, attn);
    // O-proj: M=2048, K=2048, KS=32 (Kblk=64, 2 chunks) ; +x residual
    gemm_splitk<<<dim3(16, 32), 256, 0, stream>>>(wo, wo, wo, 2048, attn, 2048, 64, pt, 2048);
    reduce_add<<<256, 256, 0, stream>>>(pt, 32, 2048, x, x2);
    rms_kernel<<<32, 256, 0, stream>>>(x2, n2w, h2);
    // MLP w1|w3: M=16384, K=2048, KS=4 (Kblk=512, 16 chunks) ; silu(g)*u
    gemm_splitk<<<dim3(128, 4), 256, 0, stream>>>(w1, w3, w3, 8192, h2, 2048, 512, pt, 16384);
    reduce_m13<<<1024, 256, 0, stream>>>(pt, ab);
    // MLP w2: M=2048, K=8192, KS=32 (Kblk=256, 8 chunks) ; +x2 residual
    gemm_splitk<<<dim3(16, 32), 256, 0, stream>>>(w2, w2, w2, 2048, ab, 8192, 256, pt, 2048);
    reduce_add<<<256, 256, 0, stream>>>(pt, 32, 2048, x2, out);
}